// Round 11
// baseline (501.191 us; speedup 1.0000x reference)
//
#include <hip/hip_runtime.h>
#include <hip/hip_bf16.h>

typedef __bf16 bf16;
typedef __bf16 bf16x8 __attribute__((ext_vector_type(8)));
typedef float  f32x4  __attribute__((ext_vector_type(4)));

static constexpr int NB  = 16;
static constexpr int NN  = 2048;
static constexpr int HID = 128;

// async 16B global -> LDS. LDS dest is wave-uniform base (+ lane*16 in HW);
// global src address IS per-lane (must carry the lane term!).
__device__ __forceinline__ void gload_lds16(const bf16* g, bf16* l) {
    __builtin_amdgcn_global_load_lds(
        (const __attribute__((address_space(1))) unsigned int*)g,
        (__attribute__((address_space(3))) unsigned int*)l, 16, 0, 0);
}

#define WAITV(n) asm volatile("s_waitcnt vmcnt(" #n ")" ::: "memory")
#define SCHEDB() __builtin_amdgcn_sched_barrier(0)

// ---------------------------------------------------------------------------
// Layouts:
//  B-tile (128 n x 64 k, 16 KB, 1024 ch): ch = n*8 + (kc ^ (n&7)), kc=k/8.
//    xTt/hT: [b][kk(32)][1024 ch].  A K=256 B-chunk = 4 consecutive tiles
//    = 64 KB linear.
//  adjFr (PER-WAVE FRAGMENT stream): [b][mt(16)][wave(8)] blocks of 32768
//    elems = 64 steps x 512 elems; step s, elem (q*16+c0)*8 + j holds
//    adj[m0 + wave*16 + c0][s*32 + q*8 + j].  A wave's step-load is 1 KB
//    contiguous; its whole K-stream is 64 KB linear.
//  WTg per layer (32 KB, 2048 ch): ch = n*16 + half*8 + (kc8 ^ (n&7)),
//    half = k>>6, kc8 = (k&63)>>3  (k-contig bf16x8 frags of W^T[n][k]).
// ---------------------------------------------------------------------------

// prep: W (128x128 fp32, [k][n]) -> swizzled WT tiles, for all 3 layers
__global__ __launch_bounds__(256) void prep_wt(const float* __restrict__ W0,
                                               const float* __restrict__ W1,
                                               const float* __restrict__ W2,
                                               bf16* __restrict__ WTg) {
    int l = blockIdx.x;
    const float* W = (l == 0) ? W0 : (l == 1) ? W1 : W2;
    bf16* out = WTg + l * 16384;
    int tid = threadIdx.x;
#pragma unroll
    for (int i = 0; i < 8; ++i) {
        int p = i * 256 + tid;                 // [0,2048)
        int n = p >> 4, half = (p >> 3) & 1, cs = p & 7;
        int kc = cs ^ (n & 7);
        int kbase = half * 64 + kc * 8;
        bf16x8 o;
#pragma unroll
        for (int r = 0; r < 8; ++r) o[r] = (bf16)W[(kbase + r) * 128 + n];
        *(bf16x8*)(out + p * 8) = o;
    }
}

// prep: x (16,2048,128) fp32 -> xTt tiled bf16 B-tiles
__global__ __launch_bounds__(256) void prep_xt(const float* __restrict__ x,
                                               bf16* __restrict__ xTt) {
    __shared__ bf16 T[128 * 136];
    const int blk = blockIdx.x;            // 256 blocks: 16 node-tiles x 16 b
    const int b = blk >> 4, node0 = (blk & 15) * 128;
    const int tid = threadIdx.x;
    const float* xb = x + ((size_t)b * NN + node0) * HID;
#pragma unroll
    for (int i = 0; i < 64; ++i) {
        int idx = i * 256 + tid;
        int node = idx >> 7, hid = idx & 127;
        T[hid * 136 + node] = (bf16)xb[(size_t)node * HID + hid];
    }
    __syncthreads();
#pragma unroll
    for (int i = 0; i < 8; ++i) {
        int p = i * 256 + tid;                 // [0,2048) chunks (2 tiles)
        int half = p >> 10, p1 = p & 1023;
        int n = p1 >> 3, cs = p1 & 7, c = cs ^ (n & 7), m = half * 64 + c * 8;
        *(bf16x8*)(xTt + ((size_t)b * 32 + (node0 >> 6) + half) * 8192 + p1 * 8)
            = *(const bf16x8*)(T + n * 136 + m);
    }
}

// ---------------------------------------------------------------------------
// Shared epilogue (acc[2][4], 8-wave wm/wn tiling) for layer0 — R7/R10-proven.
// ---------------------------------------------------------------------------
template<bool FINAL>
__device__ __forceinline__ void epilogue24(
        bf16* lds, const f32x4 (&acc)[2][4],
        const bf16* __restrict__ WTg,
        const float* __restrict__ bias, const float* __restrict__ gam,
        const float* __restrict__ bet, bf16* __restrict__ hOut,
        float* __restrict__ outF, int b, int mtile, int m0) {
    const int tid = threadIdx.x, wave = tid >> 6, lane = tid & 63;
    const int c0 = lane & 15, q = lane >> 4;
    const int wm = wave >> 1, wn = wave & 1;

    bf16* G = lds;
#pragma unroll
    for (int mt = 0; mt < 2; ++mt)
#pragma unroll
        for (int r = 0; r < 4; ++r) {
            int row = wm * 32 + mt * 16 + q * 4 + r;
#pragma unroll
            for (int nt = 0; nt < 4; ++nt) {
                int col = wn * 64 + nt * 16 + c0;
                G[row * 136 + col] = (bf16)acc[mt][nt][r];
            }
        }
    __syncthreads();

    f32x4 a2[8] = {};
    {
        const int gr = wave * 16 + c0;
#pragma unroll
        for (int ks = 0; ks < 4; ++ks) {
            bf16x8 af = *(const bf16x8*)(G + gr * 136 + ks * 32 + q * 8);
#pragma unroll
            for (int nt = 0; nt < 8; ++nt) {
                int n = nt * 16 + c0;
                int ch = n * 16 + (ks >> 1) * 8 + ((((ks & 1) << 2) | q) ^ (n & 7));
                bf16x8 bw = *(const bf16x8*)(WTg + (size_t)ch * 8);
                a2[nt] = __builtin_amdgcn_mfma_f32_16x16x32_bf16(af, bw, a2[nt], 0, 0, 0);
            }
        }
    }

    float bv[8], gv[8], ev[8];
#pragma unroll
    for (int nt = 0; nt < 8; ++nt) {
        int n = nt * 16 + c0;
        bv[nt] = bias[n]; gv[nt] = gam[n]; ev[nt] = bet[n];
    }
    bf16* Cs = lds;
    if constexpr (!FINAL) __syncthreads();
#pragma unroll
    for (int r = 0; r < 4; ++r) {
        float v[8], s1 = 0.f, s2 = 0.f;
#pragma unroll
        for (int nt = 0; nt < 8; ++nt) {
            float xv = a2[nt][r] + bv[nt];
            v[nt] = xv; s1 += xv; s2 += xv * xv;
        }
#pragma unroll
        for (int off = 1; off < 16; off <<= 1) {
            s1 += __shfl_xor(s1, off);
            s2 += __shfl_xor(s2, off);
        }
        float mu = s1 * (1.f / 128.f);
        float var = s2 * (1.f / 128.f) - mu * mu;
        float rs = rsqrtf(var + 1e-5f);
        int row = wave * 16 + q * 4 + r;
        if constexpr (FINAL) {
            size_t ro = ((size_t)b * NN + m0 + row) * HID;
#pragma unroll
            for (int nt = 0; nt < 8; ++nt) {
                float o = fmaxf((v[nt] - mu) * rs * gv[nt] + ev[nt], 0.f);
                outF[ro + nt * 16 + c0] = o;
            }
        } else {
#pragma unroll
            for (int nt = 0; nt < 8; ++nt) {
                float o = fmaxf((v[nt] - mu) * rs * gv[nt] + ev[nt], 0.f);
                Cs[(nt * 16 + c0) * 136 + row] = (bf16)o;
            }
        }
    }
    if constexpr (!FINAL) {
        __syncthreads();
#pragma unroll
        for (int i = 0; i < 4; ++i) {
            int p = i * 512 + tid;
            int half = p >> 10, p1 = p & 1023;
            int n = p1 >> 3, cs = p1 & 7, c = cs ^ (n & 7), m = half * 64 + c * 8;
            *(bf16x8*)(hOut + ((size_t)b * 32 + mtile * 2 + half) * 8192 + p1 * 8)
                = *(const bf16x8*)(Cs + n * 136 + m);
        }
    }
}

// Same epilogue for acc[8] (wave owns rows wave*16..+16, all 128 cols).
template<bool FINAL>
__device__ __forceinline__ void epilogue8(
        bf16* lds, const f32x4 (&acc)[8],
        const bf16* __restrict__ WTg,
        const float* __restrict__ bias, const float* __restrict__ gam,
        const float* __restrict__ bet, bf16* __restrict__ hOut,
        float* __restrict__ outF, int b, int mtile, int m0) {
    const int tid = threadIdx.x, wave = tid >> 6, lane = tid & 63;
    const int c0 = lane & 15, q = lane >> 4;

    bf16* G = lds;
#pragma unroll
    for (int nt = 0; nt < 8; ++nt)
#pragma unroll
        for (int r = 0; r < 4; ++r) {
            int row = wave * 16 + q * 4 + r;
            G[row * 136 + nt * 16 + c0] = (bf16)acc[nt][r];
        }
    __syncthreads();

    f32x4 a2[8] = {};
    {
        const int gr = wave * 16 + c0;
#pragma unroll
        for (int ks = 0; ks < 4; ++ks) {
            bf16x8 af = *(const bf16x8*)(G + gr * 136 + ks * 32 + q * 8);
#pragma unroll
            for (int nt = 0; nt < 8; ++nt) {
                int n = nt * 16 + c0;
                int ch = n * 16 + (ks >> 1) * 8 + ((((ks & 1) << 2) | q) ^ (n & 7));
                bf16x8 bw = *(const bf16x8*)(WTg + (size_t)ch * 8);
                a2[nt] = __builtin_amdgcn_mfma_f32_16x16x32_bf16(af, bw, a2[nt], 0, 0, 0);
            }
        }
    }

    float bv[8], gv[8], ev[8];
#pragma unroll
    for (int nt = 0; nt < 8; ++nt) {
        int n = nt * 16 + c0;
        bv[nt] = bias[n]; gv[nt] = gam[n]; ev[nt] = bet[n];
    }
    bf16* Cs = lds;
    if constexpr (!FINAL) __syncthreads();
#pragma unroll
    for (int r = 0; r < 4; ++r) {
        float v[8], s1 = 0.f, s2 = 0.f;
#pragma unroll
        for (int nt = 0; nt < 8; ++nt) {
            float xv = a2[nt][r] + bv[nt];
            v[nt] = xv; s1 += xv; s2 += xv * xv;
        }
#pragma unroll
        for (int off = 1; off < 16; off <<= 1) {
            s1 += __shfl_xor(s1, off);
            s2 += __shfl_xor(s2, off);
        }
        float mu = s1 * (1.f / 128.f);
        float var = s2 * (1.f / 128.f) - mu * mu;
        float rs = rsqrtf(var + 1e-5f);
        int row = wave * 16 + q * 4 + r;
        if constexpr (FINAL) {
            size_t ro = ((size_t)b * NN + m0 + row) * HID;
#pragma unroll
            for (int nt = 0; nt < 8; ++nt) {
                float o = fmaxf((v[nt] - mu) * rs * gv[nt] + ev[nt], 0.f);
                outF[ro + nt * 16 + c0] = o;
            }
        } else {
#pragma unroll
            for (int nt = 0; nt < 8; ++nt) {
                float o = fmaxf((v[nt] - mu) * rs * gv[nt] + ev[nt], 0.f);
                Cs[(nt * 16 + c0) * 136 + row] = (bf16)o;
            }
        }
    }
    if constexpr (!FINAL) {
        __syncthreads();
#pragma unroll
        for (int i = 0; i < 4; ++i) {
            int p = i * 512 + tid;
            int half = p >> 10, p1 = p & 1023;
            int n = p1 >> 3, cs = p1 & 7, c = cs ^ (n & 7), m = half * 64 + c * 8;
            *(bf16x8*)(hOut + ((size_t)b * 32 + mtile * 2 + half) * 8192 + p1 * 8)
                = *(const bf16x8*)(Cs + n * 136 + m);
        }
    }
}

// ---------------------------------------------------------------------------
// Layer 0 (R10 body, proven): BK=128 (16 K-steps), 2-deep pipeline; A from
// fp32 adj (512B/row segs); side-write NOW in per-wave FRAGMENT order (adjFr).
// ---------------------------------------------------------------------------
__global__ __launch_bounds__(512, 1) void layer0(
        const float* __restrict__ Af, bf16* __restrict__ adjFr,
        const bf16* __restrict__ Bt, const bf16* __restrict__ WTg,
        const float* __restrict__ bias, const float* __restrict__ gam,
        const float* __restrict__ bet, bf16* __restrict__ hOut) {
    __shared__ __align__(16) bf16 lds[65536];   // 2 x 32768 (A 16384 + B 16384)

    const int tid = threadIdx.x, wave = tid >> 6, lane = tid & 63;
    const int c0 = lane & 15, q = lane >> 4;
    const int blk = blockIdx.x, xcd = blk & 7, jj = blk >> 3;
    const int b = xcd * 2 + (jj & 1);
    const int mtile = jj >> 1, m0 = mtile * 128;
    const int wm = wave >> 1, wn = wave & 1;

    const bf16* Btb = Bt + (size_t)b * 32 * 8192;
    bf16* Afr = adjFr + ((size_t)b * 16 + mtile) * (size_t)8 * 32768;

    f32x4 acc[2][4] = {};

    auto stageB = [&](int buf, int t) {
#pragma unroll
        for (int j = 0; j < 4; ++j) {
            int cb = j * 512 + wave * 64;
            gload_lds16(Btb + (size_t)t * 16384 + (size_t)(cb + lane) * 8,
                        lds + buf * 32768 + 16384 + cb * 8);
        }
    };
    auto compute = [&](int buf) {
        const bf16* As = lds + buf * 32768;
        const bf16* Bs = As + 16384;
#pragma unroll
        for (int T = 0; T < 2; ++T)
#pragma unroll
            for (int ks = 0; ks < 2; ++ks) {
                bf16x8 af[2], bf_[4];
#pragma unroll
                for (int mt = 0; mt < 2; ++mt) {
                    int row = wm * 32 + mt * 16 + c0;
                    int cb = (ks * 4 + q) ^ (row & 7);
                    af[mt] = *(const bf16x8*)(As + T * 8192 + row * 64 + cb * 8);
                }
#pragma unroll
                for (int nt = 0; nt < 4; ++nt) {
                    int row = wn * 64 + nt * 16 + c0;
                    int cb = (ks * 4 + q) ^ (row & 7);
                    bf_[nt] = *(const bf16x8*)(Bs + T * 8192 + row * 64 + cb * 8);
                }
#pragma unroll
                for (int mt = 0; mt < 2; ++mt)
#pragma unroll
                    for (int nt = 0; nt < 4; ++nt)
                        acc[mt][nt] = __builtin_amdgcn_mfma_f32_16x16x32_bf16(
                            af[mt], bf_[nt], acc[mt][nt], 0, 0, 0);
            }
    };

    int g_row[4], g_cc[4];
#pragma unroll
    for (int j = 0; j < 4; ++j) {
        int gi = j * 512 + tid;
        g_row[j] = gi >> 4; g_cc[j] = gi & 15;   // row [0,128), chunk-col [0,16)
    }
    f32x4 va[4], vb[4];
    auto loadA = [&](int t) {
#pragma unroll
        for (int j = 0; j < 4; ++j) {
            const float* s = Af + (size_t)b * NN * NN
                           + (size_t)(m0 + g_row[j]) * NN + t * 128 + g_cc[j] * 8;
            va[j] = *(const f32x4*)s;
            vb[j] = *(const f32x4*)(s + 4);
        }
    };
    auto writeA = [&](int buf, int t) {
#pragma unroll
        for (int j = 0; j < 4; ++j) {
            bf16x8 o = {(bf16)va[j].x, (bf16)va[j].y, (bf16)va[j].z, (bf16)va[j].w,
                        (bf16)vb[j].x, (bf16)vb[j].y, (bf16)vb[j].z, (bf16)vb[j].w};
            int tile = g_cc[j] >> 3, kc = g_cc[j] & 7;
            int ch = g_row[j] * 8 + (kc ^ (g_row[j] & 7));
            *(bf16x8*)(lds + buf * 32768 + tile * 8192 + ch * 8) = o;
            // fragment-order side-write: wave w=row>>4, c0f=row&15,
            // step s = t*4 + (cc>>2), qf = cc&3
            int wf = g_row[j] >> 4, c0f = g_row[j] & 15;
            int sf = t * 4 + (g_cc[j] >> 2), qf = g_cc[j] & 3;
            *(bf16x8*)(Afr + (size_t)wf * 32768 + sf * 512 + (qf * 16 + c0f) * 8) = o;
        }
    };

    loadA(0); stageB(0, 0); writeA(0, 0);
    __syncthreads();
    int cur = 0;
    for (int t = 0; t < 16; ++t) {
        if (t < 15) { loadA(t + 1); stageB(cur ^ 1, t + 1); }
        compute(cur);
        if (t < 15) writeA(cur ^ 1, t + 1);
        __syncthreads();
        cur ^= 1;
    }

    epilogue24<false>(lds, acc, WTg, bias, gam, bet, hOut, nullptr, b, mtile, m0);
}

// ---------------------------------------------------------------------------
// Layers 1/2 ("layerW"): WAVE-PRIVATE pipelines.  8 waves x 16-row strips;
// A streamed per-wave from adjFr (1 KB/step linear, chunk-ahead reg dbuf,
// no LDS, no barriers on the A path).  B staged in K=256 chunks (64 KB,
// LDS dbuf, 8 gload_lds/wave); 8 barriers/layer total.  sched_barrier pins
// B-issue before A-issue so WAITV(8) at chunk end retires the B chunk.
// ---------------------------------------------------------------------------
template<bool FINAL>
__global__ __launch_bounds__(512, 1) void layerW(
        const bf16* __restrict__ adjFr, const bf16* __restrict__ Bt,
        const bf16* __restrict__ WTg,
        const float* __restrict__ bias, const float* __restrict__ gam,
        const float* __restrict__ bet, bf16* __restrict__ hOut,
        float* __restrict__ outF) {
    __shared__ __align__(16) bf16 lds[65536];   // 2 x 32768-elem B chunk bufs

    const int tid = threadIdx.x, wave = tid >> 6, lane = tid & 63;
    const int c0 = lane & 15, q = lane >> 4;
    const int blk = blockIdx.x, xcd = blk & 7, jj = blk >> 3;
    const int b = xcd * 2 + (jj & 1);
    const int mtile = jj >> 1, m0 = mtile * 128;

    const bf16* Btb = Bt + (size_t)b * 32 * 8192;
    const bf16* Aw  = adjFr + (((size_t)b * 16 + mtile) * 8 + wave) * 32768;

    f32x4 acc[8] = {};
    bf16x8 aE[8], aO[8];

#define ISSUE_B(CH) do {                                                      \
    _Pragma("unroll") for (int j = 0; j < 8; ++j) {                           \
        int cb = j * 512 + wave * 64;                                         \
        gload_lds16(Btb + (size_t)(CH) * 32768 + (size_t)(cb + lane) * 8,     \
                    lds + ((CH) & 1) * 32768 + cb * 8);                       \
    } SCHEDB(); } while (0)

#define ISSUE_A(DST, CH) do {                                                 \
    _Pragma("unroll") for (int s = 0; s < 8; ++s)                             \
        DST[s] = *(const bf16x8*)(Aw + ((CH) * 8 + s) * 512 + lane * 8);      \
    SCHEDB(); } while (0)

#define STEPS(CH, CUR) do {                                                   \
    const bf16* Bs_ = lds + ((CH) & 1) * 32768;                               \
    _Pragma("unroll") for (int s = 0; s < 8; ++s) {                           \
        const bf16* Bt_ = Bs_ + (s >> 1) * 8192;                              \
        int kb = (s & 1) * 4 + q;                                             \
        _Pragma("unroll") for (int nt = 0; nt < 8; ++nt) {                    \
            int row = nt * 16 + c0;                                           \
            bf16x8 bw = *(const bf16x8*)(Bt_ + row * 64 + (kb ^ (row & 7)) * 8); \
            acc[nt] = __builtin_amdgcn_mfma_f32_16x16x32_bf16(                \
                CUR[s], bw, acc[nt], 0, 0, 0);                                \
        }                                                                     \
    } } while (0)

    // prologue: B(0) + A(chunk 0); retire B(0) (last 8 outstanding = A)
    ISSUE_B(0);
    ISSUE_A(aE, 0);
    WAITV(8);
    __builtin_amdgcn_s_barrier();

    // chunks 0..6: issue B(ch+1) + A(ch+1), compute ch, retire B(ch+1)
    ISSUE_B(1); ISSUE_A(aO, 1); STEPS(0, aE); WAITV(8); __builtin_amdgcn_s_barrier();
    ISSUE_B(2); ISSUE_A(aE, 2); STEPS(1, aO); WAITV(8); __builtin_amdgcn_s_barrier();
    ISSUE_B(3); ISSUE_A(aO, 3); STEPS(2, aE); WAITV(8); __builtin_amdgcn_s_barrier();
    ISSUE_B(4); ISSUE_A(aE, 4); STEPS(3, aO); WAITV(8); __builtin_amdgcn_s_barrier();
    ISSUE_B(5); ISSUE_A(aO, 5); STEPS(4, aE); WAITV(8); __builtin_amdgcn_s_barrier();
    ISSUE_B(6); ISSUE_A(aE, 6); STEPS(5, aO); WAITV(8); __builtin_amdgcn_s_barrier();
    ISSUE_B(7); ISSUE_A(aO, 7); STEPS(6, aE); WAITV(8); __builtin_amdgcn_s_barrier();
    STEPS(7, aO);

#undef ISSUE_B
#undef ISSUE_A
#undef STEPS

    __syncthreads();    // B buffers dead; epilogue reuses LDS
    epilogue8<FINAL>(lds, acc, WTg, bias, gam, bet, hOut, outF, b, mtile, m0);
}

// ---------------------------------------------------------------------------
extern "C" void kernel_launch(void* const* d_in, const int* in_sizes, int n_in,
                              void* d_out, int out_size, void* d_ws, size_t ws_size,
                              hipStream_t stream) {
    const float* x   = (const float*)d_in[0];
    const float* adj = (const float*)d_in[1];
    const float* W[3]  = {(const float*)d_in[2],  (const float*)d_in[6],  (const float*)d_in[10]};
    const float* bb[3] = {(const float*)d_in[3],  (const float*)d_in[7],  (const float*)d_in[11]};
    const float* gg[3] = {(const float*)d_in[4],  (const float*)d_in[8],  (const float*)d_in[12]};
    const float* be[3] = {(const float*)d_in[5],  (const float*)d_in[9],  (const float*)d_in[13]};

    char* ws = (char*)d_ws;
    size_t off = 0;
    auto alloc = [&](size_t bytes) {
        char* p = ws + off; off = (off + bytes + 255) & ~(size_t)255; return p;
    };
    bf16* WTg   = (bf16*)alloc((size_t)3 * 16384 * 2);
    bf16* xTt   = (bf16*)alloc((size_t)NB * 32 * 8192 * 2);           // 8 MiB
    bf16* hT0   = (bf16*)alloc((size_t)NB * 32 * 8192 * 2);           // 8 MiB
    bf16* hT1   = (bf16*)alloc((size_t)NB * 32 * 8192 * 2);           // 8 MiB
    bf16* adjFr = (bf16*)alloc((size_t)NB * 16 * 8 * 32768 * 2);      // 128 MiB

    float* outF = (float*)d_out;

    prep_wt<<<3, 256, 0, stream>>>(W[0], W[1], W[2], WTg);
    prep_xt<<<256, 256, 0, stream>>>(x, xTt);

    layer0<<<256, 512, 0, stream>>>(adj, adjFr, xTt, WTg,
                                    bb[0], gg[0], be[0], hT0);
    layerW<false><<<256, 512, 0, stream>>>(adjFr, hT0, WTg + 16384,
                                           bb[1], gg[1], be[1], hT1, nullptr);
    layerW<true ><<<256, 512, 0, stream>>>(adjFr, hT1, WTg + 2 * 16384,
                                           bb[2], gg[2], be[2], nullptr, outF);
}